// Round 8
// baseline (605.181 us; speedup 1.0000x reference)
//
#include <hip/hip_runtime.h>

// FirstOrderCondRNN: B=256 batches, T=61 (60 scan steps).
// R8: TWO-KERNEL SPLIT. R1-R7 falsified drain/banks/TLP/locality/
// co-residency/cycle-count; window stuck at ~195us = 2.4x write floor.
// Remaining structural suspect: serial recurrence interleaved with the
// 500MB store stream in one barrier domain. Split:
//  K1 (one block/batch, R7 structure): coupled recurrence; writes only
//     r_series/readout + aux (rdan,rbd per step, 40 floats) + rk^T dump
//     to workspace. No W/wt series stores.
//  K2 (2 blocks/batch, no loop barriers): per-(b,chunk) scalar recurrence
//     over t; stages rk^T + aux into LDS once; pure streaming writer of
//     W/wt series (500MB) at fill-like occupancy.
// Shared __device__ elem_update => identical codegen in both kernels =>
// outputs bit-identical to R7 (absmax must stay exactly 0.25).
// Workspace: B*(61*200 + 60*40)*4 = 14.95 MB required.

#define NKC   200
#define NREC  100
#define TSTEP 61
#define NSTEP 60
#define PSTR  52    // padded partial row stride
#define NTHR  512

typedef float vfloat4 __attribute__((ext_vector_type(4)));

// Workgroup barrier that waits only on LDS ops (lgkmcnt), leaving global
// stores in flight (no vmcnt drain). sched_barrier(0) pins program order.
__device__ __forceinline__ void bar_lds() {
    __builtin_amdgcn_sched_barrier(0);
    asm volatile("s_waitcnt lgkmcnt(0)");
    __builtin_amdgcn_s_barrier();
    __builtin_amdgcn_sched_barrier(0);
}

__device__ __forceinline__ void nt_store4(float* p, float4 v) {
    vfloat4 t;
    t.x = v.x; t.y = v.y; t.z = v.z; t.w = v.w;
    __builtin_nontemporal_store(t, (vfloat4*)p);
}
__device__ __forceinline__ void nt_store1(float* p, float v) {
    __builtin_nontemporal_store(v, p);
}

// Per-element W/wt/rbk state update — the EXACT op sequence of R7 Phase E.
// Used by both kernels so codegen (incl. fma contraction) is identical.
__device__ __forceinline__ void elem_update(
    const float4 rk4, const float rbdn, const float rdan,
    const float dt, const float dtw,
    float4& rb, float4& wt, float4& w)
{
    rb.x += (rk4.x - rb.x) * dtw;  rb.y += (rk4.y - rb.y) * dtw;
    rb.z += (rk4.z - rb.z) * dtw;  rb.w += (rk4.w - rb.w) * dtw;
    wt.x = fmaf(rbdn * rk4.x - rdan * rb.x, dt, wt.x);
    wt.y = fmaf(rbdn * rk4.y - rdan * rb.y, dt, wt.y);
    wt.z = fmaf(rbdn * rk4.z - rdan * rb.z, dt, wt.z);
    wt.w = fmaf(rbdn * rk4.w - rdan * rb.w, dt, wt.w);
    w.x += (wt.x - w.x) * dtw;  w.y += (wt.y - w.y) * dtw;
    w.z += (wt.z - w.z) * dtw;  w.w += (wt.w - w.w) * dtw;
    w.x = fminf(fmaxf(w.x, 0.f), 0.05f);
    w.y = fminf(fmaxf(w.y, 0.f), 0.05f);
    w.z = fminf(fmaxf(w.z, 0.f), 0.05f);
    w.w = fminf(fmaxf(w.w, 0.f), 0.05f);
}

// ---------------- K1: coupled recurrence (small outputs + aux) ----------------
__global__ __launch_bounds__(NTHR, 1) void rnn_state_kernel(
    const float* __restrict__ r_kc, const float* __restrict__ r_ext,
    const float* __restrict__ timev, const float* __restrict__ W0_W,
    const float* __restrict__ W0_w, const float* __restrict__ W_recur,
    const float* __restrict__ W_ext, const float* __restrict__ bias,
    const float* __restrict__ W_readout, float* __restrict__ out,
    float* __restrict__ rkT, float* __restrict__ aux, int B)
{
    const int b   = blockIdx.x;
    const int tid = threadIdx.x;
    const float dt  = timev[1] - timev[0];   // 0.5
    const float dtw = dt / 5.0f;             // dt / TAU_W

    __shared__ __align__(16) float s_rk[TSTEP * NKC];   // [t][k], 48.8 KB
    __shared__ __align__(16) float s_re[128];           // [e][t] (2*61)
    __shared__ __align__(16) float s_Wro[32];
    __shared__ __align__(16) float s_r[2][112];         // double-buffered rates
    __shared__ __align__(16) float s_rbd[32];
    __shared__ __align__(16) float s_part[20 * PSTR];   // I_kc partials

    // stage + transpose r_kc to [t][k]
    const float* rk_b = r_kc + (size_t)b * (NKC * TSTEP);
    for (int f = tid; f < NKC * TSTEP; f += NTHR) {
        int k = f / TSTEP, t = f - k * TSTEP;
        s_rk[t * NKC + k] = rk_b[f];
    }
    const float* re_b = r_ext + (size_t)b * (2 * TSTEP);
    if (tid < 2 * TSTEP) s_re[tid] = re_b[tid];

    // Wr row in registers (tid<100), Wr[:20, 80:] = 0
    float4 wrreg[25];
    if (tid < 100) {
        const float* wrow = W_recur + tid * NREC;
        #pragma unroll
        for (int j4 = 0; j4 < 25; ++j4)
            wrreg[j4] = *(const float4*)(wrow + 4 * j4);
        if (tid < 20) {
            #pragma unroll
            for (int j4 = 20; j4 < 25; ++j4) {
                wrreg[j4].x = 0.f; wrreg[j4].y = 0.f;
                wrreg[j4].z = 0.f; wrreg[j4].w = 0.f;
            }
        }
    }

    if (tid < 20)  s_Wro[tid] = W_readout[tid];
    if (tid < 100) s_r[0][tid] = (tid < 20) ? 0.f : 0.1f;
    if (tid < 20)  s_rbd[tid] = 0.1f;

    float my_bias = 0.f, we0 = 0.f, we1 = 0.f;
    if (tid < 100) my_bias = bias[tid];
    if (tid >= 20 && tid < 80) { we0 = W_ext[(tid - 20) * 2]; we1 = W_ext[(tid - 20) * 2 + 1]; }
    float rbd_mine = 0.1f;
    float r_mine   = (tid < 20) ? 0.f : 0.1f;

    float* out_r  = out;                              // [61][B][100]
    float* out_W  = out + (size_t)TSTEP * B * 100;
    float* out_wt = out_W + (size_t)TSTEP * B * 4000;
    float* out_ro = out_wt + (size_t)TSTEP * B * 4000;// [61][B]

    // W / wt / rbk state in registers (2 chunks/thread)
    float4 Wreg[2], wtreg[2], rbkreg[2], rkc[2];
    const float* W0Wb = W0_W + (size_t)b * 4000;
    const float* W0wb = W0_w + (size_t)b * 4000;
    #pragma unroll
    for (int i = 0; i < 2; ++i) {
        int c = tid + NTHR * i;
        if (c < 1000) {
            Wreg[i]  = *(const float4*)(W0Wb + 4 * c);
            wtreg[i] = *(const float4*)(W0wb + 4 * c);
        }
    }
    if (tid < 100) nt_store1(out_r + (size_t)b * 100 + tid, r_mine);

    __syncthreads();

    // dump rk^T to workspace for K2 (linear copy of [t][k] layout)
    float* rkT_b = rkT + (size_t)b * (TSTEP * NKC);
    for (int f4 = tid; f4 < (TSTEP * NKC) / 4; f4 += NTHR) {
        float4 v = *(const float4*)(s_rk + 4 * f4);
        nt_store4(rkT_b + 4 * f4, v);
    }

    // initial rbk = rk[:,0]; initial I_kc partials = dot(W0, rk_0)
    #pragma unroll
    for (int i = 0; i < 2; ++i) {
        int c = tid + NTHR * i;
        if (c < 1000) {
            int k0 = (4 * c) % NKC;
            int m  = c / 50;
            float4 rk0 = *(const float4*)(s_rk + k0);
            rbkreg[i] = rk0;
            rkc[i]    = rk0;
            float4 w = Wreg[i];
            s_part[m * PSTR + (c % 50)] =
                w.x * rk0.x + w.y * rk0.y + w.z * rk0.z + w.w * rk0.w;
        }
    }
    if (tid == 255) {
        float ro = 0.f;
        #pragma unroll
        for (int mm = 0; mm < 20; ++mm) ro += s_Wro[mm] * s_r[0][mm];
        nt_store1(out_ro + b, ro);
    }
    __syncthreads();

    float* aux_b = aux + (size_t)b * (NSTEP * 40);

    for (int it = 0; it < NSTEP; ++it) {
        const int cur = it & 1, nxt = cur ^ 1;

        // Phase A
        if (tid < 100) {
            float acc = my_bias;
            if (tid < 20) {
                const float* pp = s_part + tid * PSTR;
                #pragma unroll
                for (int q4 = 0; q4 < 12; ++q4) {
                    float4 p4 = *(const float4*)(pp + 4 * q4);
                    acc += p4.x + p4.y + p4.z + p4.w;
                }
                acc += pp[48] + pp[49];
            } else if (tid < 80) {
                acc = fmaf(we0, s_re[it], acc);
                acc = fmaf(we1, s_re[TSTEP + it], acc);
            }
            #pragma unroll
            for (int j4 = 0; j4 < 25; ++j4) {
                float4 w4 = wrreg[j4];
                float4 r4 = *(const float4*)(&s_r[cur][4 * j4]);
                acc = fmaf(w4.x, r4.x, acc); acc = fmaf(w4.y, r4.y, acc);
                acc = fmaf(w4.z, r4.z, acc); acc = fmaf(w4.w, r4.w, acc);
            }
            float drive = acc > 0.f ? acc : 0.f;
            float rn = r_mine + dt * (drive - r_mine);   // TAU_R = 1
            r_mine = rn;
            s_r[nxt][tid] = rn;
            nt_store1(out_r + (size_t)(it + 1) * B * 100 + (size_t)b * 100 + tid, rn);
            if (tid >= 80) {
                rbd_mine += (rn - rbd_mine) * dtw;
                s_rbd[tid - 80] = rbd_mine;
                // aux for K2: rdan (r_new DAN) and rbd_new, exact bits
                nt_store1(aux_b + it * 40 + (tid - 80), rn);
                nt_store1(aux_b + it * 40 + 20 + (tid - 80), rbd_mine);
            }
        }
        bar_lds();

        // Phase E: state update + next-step partials (NO series stores)
        const float* rk_nx = s_rk + (it + 1) * NKC;
        #pragma unroll
        for (int i = 0; i < 2; ++i) {
            int c = tid + NTHR * i;
            if (c < 1000) {
                int k0 = (4 * c) % NKC;
                int m  = c / 50;
                float4 rk4 = rkc[i];
                float4 rkn = *(const float4*)(rk_nx + k0);
                rkc[i] = rkn;
                float rbdn = s_rbd[m];
                float rdan = s_r[nxt][80 + m];
                elem_update(rk4, rbdn, rdan, dt, dtw, rbkreg[i], wtreg[i], Wreg[i]);
                float4 w = Wreg[i];
                s_part[m * PSTR + (c % 50)] =
                    w.x * rkn.x + w.y * rkn.y + w.z * rkn.z + w.w * rkn.w;
            }
        }
        if (tid == 255) {
            float ro = 0.f;
            #pragma unroll
            for (int mm = 0; mm < 20; ++mm) ro += s_Wro[mm] * s_r[nxt][mm];
            nt_store1(out_ro + (size_t)(it + 1) * B + b, ro);
        }
        bar_lds();
    }
}

// ---------------- K2: W/wt series streaming writer ----------------
__global__ __launch_bounds__(NTHR, 2) void w_series_kernel(
    const float* __restrict__ W0_W, const float* __restrict__ W0_w,
    const float* __restrict__ timev,
    const float* __restrict__ rkT, const float* __restrict__ aux,
    float* __restrict__ out, int B)
{
    const int b    = blockIdx.x >> 1;
    const int half = blockIdx.x & 1;
    const int tid  = threadIdx.x;
    const float dt  = timev[1] - timev[0];
    const float dtw = dt / 5.0f;

    __shared__ __align__(16) float s_rk[TSTEP * NKC];   // 48.8 KB
    __shared__ __align__(16) float s_aux[NSTEP * 40];   // 9.6 KB

    const float* rkT_b = rkT + (size_t)b * (TSTEP * NKC);
    for (int f4 = tid; f4 < (TSTEP * NKC) / 4; f4 += NTHR)
        *(float4*)(s_rk + 4 * f4) = *(const float4*)(rkT_b + 4 * f4);
    const float* aux_b = aux + (size_t)b * (NSTEP * 40);
    for (int f4 = tid; f4 < (NSTEP * 40) / 4; f4 += NTHR)
        *(float4*)(s_aux + 4 * f4) = *(const float4*)(aux_b + 4 * f4);

    float* out_W  = out + (size_t)TSTEP * B * 100;
    float* out_wt = out_W + (size_t)TSTEP * B * 4000;

    const bool active = (tid < 500);
    const int  c = half * 500 + tid;

    float4 w, wt, rb, rkc;
    if (active) {
        w  = *(const float4*)(W0_W + (size_t)b * 4000 + 4 * c);
        wt = *(const float4*)(W0_w + (size_t)b * 4000 + 4 * c);
        nt_store4(out_W  + (size_t)b * 4000 + 4 * c, w);    // t=0 dumps
        nt_store4(out_wt + (size_t)b * 4000 + 4 * c, wt);
    }
    __syncthreads();
    if (!active) return;

    const int k0 = (4 * c) % NKC;
    const int m  = c / 50;
    rkc = *(const float4*)(s_rk + k0);   // t = 0 row
    rb  = rkc;

    for (int it = 0; it < NSTEP; ++it) {
        float4 rkn = *(const float4*)(s_rk + (it + 1) * NKC + k0);
        float rdan = s_aux[it * 40 + m];
        float rbdn = s_aux[it * 40 + 20 + m];
        elem_update(rkc, rbdn, rdan, dt, dtw, rb, wt, w);
        rkc = rkn;
        float* oW  = out_W  + (size_t)(it + 1) * B * 4000 + (size_t)b * 4000;
        float* owt = out_wt + (size_t)(it + 1) * B * 4000 + (size_t)b * 4000;
        nt_store4(owt + 4 * c, wt);
        nt_store4(oW  + 4 * c, w);
    }
}

extern "C" void kernel_launch(void* const* d_in, const int* in_sizes, int n_in,
                              void* d_out, int out_size, void* d_ws, size_t ws_size,
                              hipStream_t stream) {
    const float* r_kc      = (const float*)d_in[0];
    const float* r_ext     = (const float*)d_in[1];
    const float* timev     = (const float*)d_in[2];
    // d_in[3] = n_batch (int scalar) — shape derived from in_sizes instead
    const float* W0_W      = (const float*)d_in[4];
    const float* W0_w      = (const float*)d_in[5];
    const float* W_recur   = (const float*)d_in[6];
    const float* W_ext     = (const float*)d_in[7];
    const float* bias      = (const float*)d_in[8];
    const float* W_readout = (const float*)d_in[9];

    const int B = in_sizes[0] / (NKC * TSTEP);   // 256
    float* ws  = (float*)d_ws;
    float* rkT = ws;                                   // B*61*200 floats
    float* aux = ws + (size_t)B * (TSTEP * NKC);       // B*60*40 floats

    rnn_state_kernel<<<dim3(B), dim3(NTHR), 0, stream>>>(
        r_kc, r_ext, timev, W0_W, W0_w, W_recur, W_ext, bias, W_readout,
        (float*)d_out, rkT, aux, B);
    w_series_kernel<<<dim3(2 * B), dim3(NTHR), 0, stream>>>(
        W0_W, W0_w, timev, rkT, aux, (float*)d_out, B);
}

// Round 9
// 510.551 us; speedup vs baseline: 1.1853x; 1.1853x over previous
//
#include <hip/hip_runtime.h>

// FirstOrderCondRNN: B=256 batches, T=61 (60 scan steps).
// One block per batch; all recurrent state on-chip.
// R9: BREAK THE SERIAL FP CHAIN (first FP-order change). R8's split
// decomposed the window: recurrence ~180us, stores ~100us (hidden when
// fused). The recurrence's serial content is Phase A's 100-fmaf dependent
// chain (Wr.r) + linear 50-term MBON partial sum. Reassociate both:
//  - Wr.r: 4 independent accumulators (chain 400 -> ~120 cyc)
//  - MBON partials: pairwise float4 tree (60 -> ~25 cyc)
//  - readout: tree-sum (hygiene)
// Base = R7 (516us, best): Wr in regs, 512 thr, bar_lds, XCD swizzle,
// nt stores, full s_rk stage, rk reg carry. absmax may move off 0.25.

#define NKC   200
#define NREC  100
#define TSTEP 61
#define NSTEP 60
#define PSTR  52    // padded partial row stride
#define NTHR  512

typedef float vfloat4 __attribute__((ext_vector_type(4)));

// Workgroup barrier that waits only on LDS ops (lgkmcnt), leaving global
// stores in flight (no vmcnt drain). sched_barrier(0) pins program order.
__device__ __forceinline__ void bar_lds() {
    __builtin_amdgcn_sched_barrier(0);
    asm volatile("s_waitcnt lgkmcnt(0)");
    __builtin_amdgcn_s_barrier();
    __builtin_amdgcn_sched_barrier(0);
}

__device__ __forceinline__ void nt_store4(float* p, float4 v) {
    vfloat4 t;
    t.x = v.x; t.y = v.y; t.z = v.z; t.w = v.w;
    __builtin_nontemporal_store(t, (vfloat4*)p);
}
__device__ __forceinline__ void nt_store1(float* p, float v) {
    __builtin_nontemporal_store(v, p);
}

__global__ __launch_bounds__(NTHR, 1) void cond_rnn_kernel(
    const float* __restrict__ r_kc, const float* __restrict__ r_ext,
    const float* __restrict__ timev, const float* __restrict__ W0_W,
    const float* __restrict__ W0_w, const float* __restrict__ W_recur,
    const float* __restrict__ W_ext, const float* __restrict__ bias,
    const float* __restrict__ W_readout, float* __restrict__ out, int B)
{
    // XCD-aware bijective swizzle (B=256, 8 XCDs).
    int b = blockIdx.x;
    if ((B & 7) == 0) {
        const int cpx = B >> 3;                  // blocks per XCD
        b = (blockIdx.x & 7) * cpx + (blockIdx.x >> 3);
    }
    const int tid = threadIdx.x;
    const float dt  = timev[1] - timev[0];   // 0.5
    const float dtw = dt / 5.0f;             // dt / TAU_W

    __shared__ __align__(16) float s_rk[TSTEP * NKC];   // [t][k], 48.8 KB
    __shared__ __align__(16) float s_re[128];           // [e][t] (2*61)
    __shared__ __align__(16) float s_Wro[32];
    __shared__ __align__(16) float s_r[2][112];         // double-buffered rates
    __shared__ __align__(16) float s_rbd[32];
    __shared__ __align__(16) float s_part[20 * PSTR];   // I_kc partials

    // ---------------- init: stage batch inputs into LDS ----------------
    const float* rk_b = r_kc + (size_t)b * (NKC * TSTEP);
    for (int f = tid; f < NKC * TSTEP; f += NTHR) {
        int k = f / TSTEP, t = f - k * TSTEP;
        s_rk[t * NKC + k] = rk_b[f];               // transpose to [t][k]
    }
    const float* re_b = r_ext + (size_t)b * (2 * TSTEP);
    if (tid < 2 * TSTEP) s_re[tid] = re_b[tid];

    // Wr row in registers (tid<100), Wr[:20, 80:] = 0
    float4 wrreg[25];
    if (tid < 100) {
        const float* wrow = W_recur + tid * NREC;
        #pragma unroll
        for (int j4 = 0; j4 < 25; ++j4)
            wrreg[j4] = *(const float4*)(wrow + 4 * j4);
        if (tid < 20) {
            #pragma unroll
            for (int j4 = 20; j4 < 25; ++j4) {
                wrreg[j4].x = 0.f; wrreg[j4].y = 0.f;
                wrreg[j4].z = 0.f; wrreg[j4].w = 0.f;
            }
        }
    }

    if (tid < 20)  s_Wro[tid] = W_readout[tid];
    if (tid < 100) s_r[0][tid] = (tid < 20) ? 0.f : 0.1f;
    if (tid < 20)  s_rbd[tid] = 0.1f;

    float my_bias = 0.f, we0 = 0.f, we1 = 0.f;
    if (tid < 100) my_bias = bias[tid];
    if (tid >= 20 && tid < 80) { we0 = W_ext[(tid - 20) * 2]; we1 = W_ext[(tid - 20) * 2 + 1]; }
    float rbd_mine = 0.1f;
    float r_mine   = (tid < 20) ? 0.f : 0.1f;

    // output sections
    float* out_r  = out;                              // [61][B][100]
    float* out_W  = out + (size_t)TSTEP * B * 100;    // [61][B][4000]
    float* out_wt = out_W + (size_t)TSTEP * B * 4000; // [61][B][4000]
    float* out_ro = out_wt + (size_t)TSTEP * B * 4000;// [61][B]

    // W / wt / rbk in registers: 2 float4 chunks per thread (chunk c = tid+512*i)
    float4 Wreg[2], wtreg[2], rbkreg[2], rkc[2];
    const float* W0Wb = W0_W + (size_t)b * 4000;
    const float* W0wb = W0_w + (size_t)b * 4000;
    #pragma unroll
    for (int i = 0; i < 2; ++i) {
        int c = tid + NTHR * i;
        if (c < 1000) {
            Wreg[i]  = *(const float4*)(W0Wb + 4 * c);
            wtreg[i] = *(const float4*)(W0wb + 4 * c);
            nt_store4(out_W  + (size_t)b * 4000 + 4 * c, Wreg[i]);   // t=0 dumps
            nt_store4(out_wt + (size_t)b * 4000 + 4 * c, wtreg[i]);
        }
    }
    if (tid < 100) nt_store1(out_r + (size_t)b * 100 + tid, r_mine);

    __syncthreads();

    // initial rbk = rk[:,0]; initial I_kc partials = dot(W0, rk_0);
    // rkc carries rk row `it` for this thread's chunks.
    #pragma unroll
    for (int i = 0; i < 2; ++i) {
        int c = tid + NTHR * i;
        if (c < 1000) {
            int k0 = (4 * c) % NKC;
            int m  = c / 50;
            float4 rk0 = *(const float4*)(s_rk + k0);   // t = 0 row
            rbkreg[i] = rk0;
            rkc[i]    = rk0;
            float4 w = Wreg[i];
            s_part[m * PSTR + (c % 50)] =
                w.x * rk0.x + w.y * rk0.y + w.z * rk0.z + w.w * rk0.w;
        }
    }
    if (tid == 255) {
        float ro = 0.f;
        #pragma unroll
        for (int mm = 0; mm < 20; ++mm) ro += s_Wro[mm] * s_r[0][mm];
        nt_store1(out_ro + b, ro);   // t=0 readout
    }
    __syncthreads();

    // ---------------- time loop ----------------
    for (int it = 0; it < NSTEP; ++it) {
        const int cur = it & 1, nxt = cur ^ 1;

        // Phase A: drive = bias + Wr·r + I_tot ; r_new ; rbd_new
        if (tid < 100) {
            float acc = my_bias;
            if (tid < 20) {                       // MBON: + I_kc, tree-summed
                const float* pp = s_part + tid * PSTR;
                float4 s01 = *(const float4*)(pp + 0)  + *(const float4*)(pp + 4);
                float4 s23 = *(const float4*)(pp + 8)  + *(const float4*)(pp + 12);
                float4 s45 = *(const float4*)(pp + 16) + *(const float4*)(pp + 20);
                float4 s67 = *(const float4*)(pp + 24) + *(const float4*)(pp + 28);
                float4 s89 = *(const float4*)(pp + 32) + *(const float4*)(pp + 36);
                float4 sab = *(const float4*)(pp + 40) + *(const float4*)(pp + 44);
                float4 t0 = s01 + s23;
                float4 t1 = s45 + s67;
                float4 t2 = s89 + sab;
                float4 u  = t0 + t1;
                u = u + t2;
                float tail = (pp[48] + pp[49]);
                acc += ((u.x + u.y) + (u.z + u.w)) + tail;
            } else if (tid < 80) {                // FBN: + W_ext · re_t
                acc = fmaf(we0, s_re[it], acc);
                acc = fmaf(we1, s_re[TSTEP + it], acc);
            }
            // Wr·r with 4 independent accumulator chains (25 j4 -> 4 strided)
            float a0 = 0.f, a1 = 0.f, a2 = 0.f, a3 = 0.f;
            #pragma unroll
            for (int j4 = 0; j4 < 24; j4 += 4) {
                {
                    float4 w4 = wrreg[j4];
                    float4 r4 = *(const float4*)(&s_r[cur][4 * j4]);
                    a0 = fmaf(w4.x, r4.x, a0); a0 = fmaf(w4.y, r4.y, a0);
                    a0 = fmaf(w4.z, r4.z, a0); a0 = fmaf(w4.w, r4.w, a0);
                }
                {
                    float4 w4 = wrreg[j4 + 1];
                    float4 r4 = *(const float4*)(&s_r[cur][4 * (j4 + 1)]);
                    a1 = fmaf(w4.x, r4.x, a1); a1 = fmaf(w4.y, r4.y, a1);
                    a1 = fmaf(w4.z, r4.z, a1); a1 = fmaf(w4.w, r4.w, a1);
                }
                {
                    float4 w4 = wrreg[j4 + 2];
                    float4 r4 = *(const float4*)(&s_r[cur][4 * (j4 + 2)]);
                    a2 = fmaf(w4.x, r4.x, a2); a2 = fmaf(w4.y, r4.y, a2);
                    a2 = fmaf(w4.z, r4.z, a2); a2 = fmaf(w4.w, r4.w, a2);
                }
                {
                    float4 w4 = wrreg[j4 + 3];
                    float4 r4 = *(const float4*)(&s_r[cur][4 * (j4 + 3)]);
                    a3 = fmaf(w4.x, r4.x, a3); a3 = fmaf(w4.y, r4.y, a3);
                    a3 = fmaf(w4.z, r4.z, a3); a3 = fmaf(w4.w, r4.w, a3);
                }
            }
            {   // j4 = 24 tail
                float4 w4 = wrreg[24];
                float4 r4 = *(const float4*)(&s_r[cur][96]);
                a0 = fmaf(w4.x, r4.x, a0); a0 = fmaf(w4.y, r4.y, a0);
                a0 = fmaf(w4.z, r4.z, a0); a0 = fmaf(w4.w, r4.w, a0);
            }
            acc += (a0 + a1) + (a2 + a3);
            float drive = acc > 0.f ? acc : 0.f;  // relu
            float rn = r_mine + dt * (drive - r_mine);   // TAU_R = 1
            r_mine = rn;
            s_r[nxt][tid] = rn;
            nt_store1(out_r + (size_t)(it + 1) * B * 100 + (size_t)b * 100 + tid, rn);
            if (tid >= 80) {                      // DAN: rbd update
                rbd_mine += (rn - rbd_mine) * dtw;
                s_rbd[tid - 80] = rbd_mine;
            }
        }
        bar_lds();

        // Phase E: rbk / wt / W updates, next-step partials, global stores
        float* oW  = out_W  + (size_t)(it + 1) * B * 4000 + (size_t)b * 4000;
        float* owt = out_wt + (size_t)(it + 1) * B * 4000 + (size_t)b * 4000;
        const float* rk_nx  = s_rk + (it + 1) * NKC;
        #pragma unroll
        for (int i = 0; i < 2; ++i) {
            int c = tid + NTHR * i;
            if (c < 1000) {
                int k0 = (4 * c) % NKC;
                int m  = c / 50;
                float4 rk4 = rkc[i];                        // carried row `it`
                float4 rkn = *(const float4*)(rk_nx + k0);  // row `it+1`
                rkc[i] = rkn;
                float rbdn = s_rbd[m];
                float rdan = s_r[nxt][80 + m];
                float4 rb = rbkreg[i];
                rb.x += (rk4.x - rb.x) * dtw;  rb.y += (rk4.y - rb.y) * dtw;
                rb.z += (rk4.z - rb.z) * dtw;  rb.w += (rk4.w - rb.w) * dtw;
                rbkreg[i] = rb;
                float4 wt = wtreg[i];
                wt.x = fmaf(rbdn * rk4.x - rdan * rb.x, dt, wt.x);
                wt.y = fmaf(rbdn * rk4.y - rdan * rb.y, dt, wt.y);
                wt.z = fmaf(rbdn * rk4.z - rdan * rb.z, dt, wt.z);
                wt.w = fmaf(rbdn * rk4.w - rdan * rb.w, dt, wt.w);
                wtreg[i] = wt;
                float4 w = Wreg[i];
                w.x += (wt.x - w.x) * dtw;  w.y += (wt.y - w.y) * dtw;
                w.z += (wt.z - w.z) * dtw;  w.w += (wt.w - w.w) * dtw;
                w.x = fminf(fmaxf(w.x, 0.f), 0.05f);
                w.y = fminf(fmaxf(w.y, 0.f), 0.05f);
                w.z = fminf(fmaxf(w.z, 0.f), 0.05f);
                w.w = fminf(fmaxf(w.w, 0.f), 0.05f);
                Wreg[i] = w;
                // partial dot for NEXT step's I_kc (uses rk at it+1)
                s_part[m * PSTR + (c % 50)] =
                    w.x * rkn.x + w.y * rkn.y + w.z * rkn.z + w.w * rkn.w;
                nt_store4(owt + 4 * c, wt);
                nt_store4(oW  + 4 * c, w);
            }
        }
        if (tid == 255) {   // readout from r_new MBONs (tree)
            const float* rr = &s_r[nxt][0];
            float q0 = 0.f, q1 = 0.f, q2 = 0.f, q3 = 0.f;
            #pragma unroll
            for (int mm = 0; mm < 20; mm += 4) {
                q0 = fmaf(s_Wro[mm],     rr[mm],     q0);
                q1 = fmaf(s_Wro[mm + 1], rr[mm + 1], q1);
                q2 = fmaf(s_Wro[mm + 2], rr[mm + 2], q2);
                q3 = fmaf(s_Wro[mm + 3], rr[mm + 3], q3);
            }
            nt_store1(out_ro + (size_t)(it + 1) * B + b, (q0 + q1) + (q2 + q3));
        }
        bar_lds();
    }
}

extern "C" void kernel_launch(void* const* d_in, const int* in_sizes, int n_in,
                              void* d_out, int out_size, void* d_ws, size_t ws_size,
                              hipStream_t stream) {
    const float* r_kc      = (const float*)d_in[0];
    const float* r_ext     = (const float*)d_in[1];
    const float* timev     = (const float*)d_in[2];
    // d_in[3] = n_batch (int scalar) — shape derived from in_sizes instead
    const float* W0_W      = (const float*)d_in[4];
    const float* W0_w      = (const float*)d_in[5];
    const float* W_recur   = (const float*)d_in[6];
    const float* W_ext     = (const float*)d_in[7];
    const float* bias      = (const float*)d_in[8];
    const float* W_readout = (const float*)d_in[9];

    const int B = in_sizes[0] / (NKC * TSTEP);   // 256
    cond_rnn_kernel<<<dim3(B), dim3(NTHR), 0, stream>>>(
        r_kc, r_ext, timev, W0_W, W0_w, W_recur, W_ext, bias, W_readout,
        (float*)d_out, B);
}